// Round 3
// baseline (172.537 us; speedup 1.0000x reference)
//
#include <hip/hip_runtime.h>
#include <hip/hip_bf16.h>
#include <stdint.h>

#define MDIM 8192
#define KDIM 1024
#define NDIM 1024
#define NEXP 8
#define BM 64     // m-tile (halved from 128: grid 568 -> ~1080, 4.2 blocks/CU)
#define BN 128
#define BK 32
#define LDSS 40   // fallback-kernel LDS stride

typedef __attribute__((ext_vector_type(8))) short bf16x8;
typedef __attribute__((ext_vector_type(4))) float floatx4;
typedef __attribute__((ext_vector_type(8))) unsigned short ushort8;

static __device__ __forceinline__ unsigned short f2b(float f) {
    // fp32 -> bf16 round-to-nearest-even (inputs finite)
    unsigned int u = __float_as_uint(f);
    return (unsigned short)((u + 0x7fffu + ((u >> 16) & 1u)) >> 16);
}

// ---------------- pass 1: fp32 -> bf16 (a and b) into workspace ----------------
// 16,777,216 elems, 8/thread -> 8192 blocks x 256 (exact). ~96 MB traffic, near HBM floor.
__global__ __launch_bounds__(256)
void cvt_bf16(const float* __restrict__ a, const float* __restrict__ b,
              unsigned short* __restrict__ wa, unsigned short* __restrict__ wb)
{
    const long t  = (long)blockIdx.x * 256 + threadIdx.x;
    const long NA = (long)MDIM * KDIM / 8;
    const float* src; unsigned short* dst; long v;
    if (t < NA) { src = a; dst = wa; v = t; }
    else        { src = b; dst = wb; v = t - NA; }
    const float4 lo = ((const float4*)src)[2 * v];
    const float4 hi = ((const float4*)src)[2 * v + 1];
    ushort8 o;
    o[0] = f2b(lo.x); o[1] = f2b(lo.y); o[2] = f2b(lo.z); o[3] = f2b(lo.w);
    o[4] = f2b(hi.x); o[5] = f2b(hi.y); o[6] = f2b(hi.z); o[7] = f2b(hi.w);
    ((ushort8*)dst)[v] = o;
}

// ---------------- pass 2: bf16 GEMM, 64x128 tiles, global_load_lds staging ------
#define GLDS(gp, lp) __builtin_amdgcn_global_load_lds(                        \
    (const __attribute__((address_space(1))) unsigned int*)(gp),              \
    (__attribute__((address_space(3))) unsigned int*)(lp), 16, 0, 0)

__global__ __launch_bounds__(256, 4)   // 4 waves/EU -> 4 blocks/CU of 256 thr
void grouped_gemm_ws(const unsigned short* __restrict__ A,   // [M,K] bf16
                     const unsigned short* __restrict__ B,   // [E,N,K] bf16
                     const int* __restrict__ seg_indptr,
                     const int* __restrict__ widx,
                     float* __restrict__ c)
{
    // unpadded row-major [row][k], 64 B row stride — required by global_load_lds
    __shared__ unsigned short As[BM * BK];   // 4 KB
    __shared__ unsigned short Bs[BN * BK];   // 8 KB

    const int NTN = NDIM / BN;  // 8
    int rem = (int)blockIdx.x;
    int s = -1, m0 = 0, seg_end = 0, n0 = 0;
    for (int i = 0; i < NEXP; ++i) {
        int ps = seg_indptr[i], pe = seg_indptr[i + 1];
        int nt = ((pe - ps + BM - 1) / BM) * NTN;
        if (rem < nt) { s = i; m0 = ps + (rem / NTN) * BM; n0 = (rem % NTN) * BN; seg_end = pe; break; }
        rem -= nt;
    }
    if (s < 0) return;  // surplus block (worst-case grid)

    const unsigned short* __restrict__ be = B + (size_t)widx[s] * (size_t)(NDIM * KDIM);

    const int tid  = (int)threadIdx.x;
    const int wave = tid >> 6;
    const int lane = tid & 63;
    // staging: thread -> row tid/4 (0..63), 16B chunk (tid&3)*8 bf16.
    // wave-uniform LDS base + lane*16B == row*64B + chunk*16B  (verified arithmetic: w*512 + l*8 elems)
    const int srow = tid >> 2;
    const int skc  = (tid & 3) * 8;
    int arow = m0 + srow; if (arow >= MDIM) arow = MDIM - 1;  // clamp; stores masked
    const int brow0 = n0 + srow, brow1 = n0 + 64 + srow;
    const int ldsoff = wave * 16 * BK;  // wave-uniform LDS offset (elements)

    const int wm = (wave & 1) * 32;     // 2x2 waves, each 32x64
    const int wn = (wave >> 1) * 64;
    const int fr = lane & 15;
    const int quad = lane >> 4;

    floatx4 acc[2][4] = {};

    const unsigned short* aptr  = A  + (size_t)arow  * KDIM + skc;
    const unsigned short* bptr0 = be + (size_t)brow0 * KDIM + skc;
    const unsigned short* bptr1 = be + (size_t)brow1 * KDIM + skc;

    for (int k0 = 0; k0 < KDIM; k0 += BK) {
        GLDS(aptr  + k0, &As[ldsoff]);
        GLDS(bptr0 + k0, &Bs[ldsoff]);
        GLDS(bptr1 + k0, &Bs[64 * BK + ldsoff]);
        __syncthreads();  // drains vmcnt -> tiles visible

        bf16x8 af[2], bf[4];
#pragma unroll
        for (int mi = 0; mi < 2; ++mi)
            af[mi] = *reinterpret_cast<const bf16x8*>(&As[(wm + mi * 16 + fr) * BK + quad * 8]);
#pragma unroll
        for (int ni = 0; ni < 4; ++ni)
            bf[ni] = *reinterpret_cast<const bf16x8*>(&Bs[(wn + ni * 16 + fr) * BK + quad * 8]);
#pragma unroll
        for (int mi = 0; mi < 2; ++mi)
#pragma unroll
            for (int ni = 0; ni < 4; ++ni)
                acc[mi][ni] = __builtin_amdgcn_mfma_f32_16x16x32_bf16(af[mi], bf[ni], acc[mi][ni], 0, 0, 0);
        __syncthreads();  // ds_reads done before next iter's staging overwrites
    }

    // epilogue: C/D layout col=lane&15, row=quad*4+reg (m89-verified); mask partial rows
#pragma unroll
    for (int mi = 0; mi < 2; ++mi) {
        const int rbase = m0 + wm + mi * 16 + quad * 4;
#pragma unroll
        for (int ni = 0; ni < 4; ++ni) {
            const int col = n0 + wn + ni * 16 + fr;
#pragma unroll
            for (int j = 0; j < 4; ++j) {
                const int row = rbase + j;
                if (row < seg_end)
                    c[(size_t)row * NDIM + col] = acc[mi][ni][j];
            }
        }
    }
}

// ---------------- fallback (R1 fused kernel) if workspace is too small ----------
__global__ __launch_bounds__(256, 2)
void grouped_gemm_fused(const float* __restrict__ a, const float* __restrict__ b,
                        const int* __restrict__ seg_indptr, const int* __restrict__ widx,
                        float* __restrict__ c)
{
    __shared__ unsigned short Asf[128 * LDSS];
    __shared__ unsigned short Bsf[128 * LDSS];
    const int NTN = NDIM / 128;
    int rem = (int)blockIdx.x;
    int s = -1, m0 = 0, seg_end = 0, n0 = 0;
    for (int i = 0; i < NEXP; ++i) {
        int ps = seg_indptr[i], pe = seg_indptr[i + 1];
        int nt = ((pe - ps + 127) / 128) * NTN;
        if (rem < nt) { s = i; m0 = ps + (rem / NTN) * 128; n0 = (rem % NTN) * 128; seg_end = pe; break; }
        rem -= nt;
    }
    if (s < 0) return;
    const float* __restrict__ be = b + (size_t)widx[s] * (size_t)(NDIM * KDIM);
    const int tid = (int)threadIdx.x;
    const int r0 = tid >> 3;
    const int kc = (tid & 7) * 4;
    int arow[4];
#pragma unroll
    for (int u = 0; u < 4; ++u) {
        int r = m0 + r0 + 32 * u;
        arow[u] = r < MDIM ? r : MDIM - 1;
    }
    const int lane = tid & 63;
    const int wave = tid >> 6;
    const int wm = (wave & 1) * 64;
    const int wn = (wave >> 1) * 64;
    const int fr = lane & 15;
    const int quad = lane >> 4;
    floatx4 acc[4][4] = {};
    float4 av[4], bv[4];
#pragma unroll
    for (int u = 0; u < 4; ++u) {
        av[u] = *reinterpret_cast<const float4*>(a + (size_t)arow[u] * KDIM + kc);
        bv[u] = *reinterpret_cast<const float4*>(be + (size_t)(n0 + r0 + 32 * u) * KDIM + kc);
    }
    for (int k0 = 0; k0 < KDIM; k0 += BK) {
        __syncthreads();
#pragma unroll
        for (int u = 0; u < 4; ++u) {
            ushort4 ua, ub;
            ua.x = f2b(av[u].x); ua.y = f2b(av[u].y); ua.z = f2b(av[u].z); ua.w = f2b(av[u].w);
            ub.x = f2b(bv[u].x); ub.y = f2b(bv[u].y); ub.z = f2b(bv[u].z); ub.w = f2b(bv[u].w);
        *reinterpret_cast<ushort4*>(&Asf[(r0 + 32 * u) * LDSS + kc]) = ua;
        *reinterpret_cast<ushort4*>(&Bsf[(r0 + 32 * u) * LDSS + kc]) = ub;
        }
        const int kn = (k0 + BK < KDIM) ? (k0 + BK) : 0;
#pragma unroll
        for (int u = 0; u < 4; ++u) {
            av[u] = *reinterpret_cast<const float4*>(a + (size_t)arow[u] * KDIM + kn + kc);
            bv[u] = *reinterpret_cast<const float4*>(be + (size_t)(n0 + r0 + 32 * u) * KDIM + kn + kc);
        }
        __syncthreads();
        bf16x8 af[4], bf[4];
#pragma unroll
        for (int mi = 0; mi < 4; ++mi)
            af[mi] = *reinterpret_cast<const bf16x8*>(&Asf[(wm + mi * 16 + fr) * LDSS + quad * 8]);
#pragma unroll
        for (int ni = 0; ni < 4; ++ni)
            bf[ni] = *reinterpret_cast<const bf16x8*>(&Bsf[(wn + ni * 16 + fr) * LDSS + quad * 8]);
#pragma unroll
        for (int mi = 0; mi < 4; ++mi)
#pragma unroll
            for (int ni = 0; ni < 4; ++ni)
                acc[mi][ni] = __builtin_amdgcn_mfma_f32_16x16x32_bf16(af[mi], bf[ni], acc[mi][ni], 0, 0, 0);
    }
#pragma unroll
    for (int mi = 0; mi < 4; ++mi) {
        const int rbase = m0 + wm + mi * 16 + quad * 4;
#pragma unroll
        for (int ni = 0; ni < 4; ++ni) {
            const int col = n0 + wn + ni * 16 + fr;
#pragma unroll
            for (int j = 0; j < 4; ++j) {
                const int row = rbase + j;
                if (row < seg_end)
                    c[(size_t)row * NDIM + col] = acc[mi][ni][j];
            }
        }
    }
}

extern "C" void kernel_launch(void* const* d_in, const int* in_sizes, int n_in,
                              void* d_out, int out_size, void* d_ws, size_t ws_size,
                              hipStream_t stream) {
    const float* a          = (const float*)d_in[0];
    const float* b          = (const float*)d_in[1];
    const int*   seg_indptr = (const int*)d_in[5];
    const int*   widx       = (const int*)d_in[6];
    float*       out        = (float*)d_out;

    const size_t need = (size_t)(MDIM + NEXP * NDIM) * KDIM * sizeof(unsigned short); // 32 MiB
    if (ws_size >= need) {
        unsigned short* wa = (unsigned short*)d_ws;                       // [M,K] bf16
        unsigned short* wb = wa + (size_t)MDIM * KDIM;                    // [E,N,K] bf16
        hipLaunchKernelGGL(cvt_bf16, dim3(8192), dim3(256), 0, stream, a, b, wa, wb);
        // worst-case tiles: sum ceil(len_s/64) <= 8192/64 + 7 = 135 row-tiles, x8 col-tiles
        hipLaunchKernelGGL(grouped_gemm_ws, dim3(135 * 8), dim3(256), 0, stream,
                           wa, wb, seg_indptr, widx, out);
    } else {
        hipLaunchKernelGGL(grouped_gemm_fused, dim3(568), dim3(256), 0, stream,
                           a, b, seg_indptr, widx, out);
    }
}